// Round 16
// baseline (224.950 us; speedup 1.0000x reference)
//
#include <hip/hip_runtime.h>
#include <math.h>

constexpr int V = 128;   // vocab (fixed for this instance)

// ---- DPP wave-wide shifts (VALU, no LDS pipe, no lgkm wait) ----
__device__ __forceinline__ double dpp_shr1_f64(double x) {
    int lo = __builtin_amdgcn_update_dpp(0, __double2loint(x), 0x138, 0xf, 0xf, false);
    int hi = __builtin_amdgcn_update_dpp(0, __double2hiint(x), 0x138, 0xf, 0xf, false);
    return __hiloint2double(hi, lo);
}
__device__ __forceinline__ double dpp_shl1_f64(double x) {
    int lo = __builtin_amdgcn_update_dpp(0, __double2loint(x), 0x130, 0xf, 0xf, false);
    int hi = __builtin_amdgcn_update_dpp(0, __double2hiint(x), 0x130, 0xf, 0xf, false);
    return __hiloint2double(hi, lo);
}

__device__ __forceinline__ unsigned f32_to_bf16_rne(float f) {
    unsigned u = __float_as_uint(f);
    return (u + 0x7fffu + ((u >> 16) & 1u)) >> 16;
}

// ======================= PATH A ============================================
// MEASURED MAP (15 rounds):
// - r17 two-kernel f64 depth-16: scan 81us, total 166 (verified baseline).
// - Scan 190cyc/step = ~95 issue + ~95 DEPENDENCY stall; invariant to
//   {state dtype, depth, traffic, memory path} (r10-r19). r19 only proved
//   another WAVE doesn't interfere (different SIMD) - it never tested
//   IN-STREAM ILP.
// - Fusion of prelude work into the scan kernel is structurally dead
//   (r20-r23: producers on 3 waves x 64 blocks can't match a 16K-block
//   grid's TLP).
// r25: LAST LEVER - interleave the fwd and bwd chains IN ONE WAVE
//   (B blocks). Two independent dep chains share one instruction stream;
//   each chain's issue fills the other's stall. bf16 g (r18-verified
//   absmax 0.0) keeps both 16-deep rings at 64 VGPR total. Junction is an
//   in-register dot (same wave holds both halves) - rendezvous eliminated.
//   Step bodies byte-identical to r17/r18 verified math.
__global__ __launch_bounds__(256) void ctc_prelude(
    const float* __restrict__ pred, const int* __restrict__ gt,
    const int* __restrict__ gt_len, const int* __restrict__ pred_len,
    char* __restrict__ g16, float* __restrict__ z, int* __restrict__ flags,
    int T, int S)
{
    // fused flag-zeroing: gdone (+ spare)
    if (blockIdx.x == 0 && threadIdx.x < 65) flags[threadIdx.x] = 0;

    int wid  = blockIdx.x * 4 + (threadIdx.x >> 6);
    int lane = threadIdx.x & 63;
    int w4   = threadIdx.x >> 6;
    int b    = wid / T;
    int t    = wid - b * T;
    if (t >= pred_len[b]) return;     // wave-uniform: rows beyond len unread
    __shared__ float rows[4][V];      // wave-private regions: no barrier

    const float2* p = (const float2*)pred + (size_t)wid * 64;
    float2 v = p[lane];
    rows[w4][2 * lane]     = v.x;
    rows[w4][2 * lane + 1] = v.y;
    float x0 = __shfl(v.x, 0, 64);
    float s = __expf(v.x) + __expf(v.y);
    #pragma unroll
    for (int off = 32; off >= 1; off >>= 1) s += __shfl_xor(s, off, 64);
    if (lane == 0) z[wid] = __logf(s) - v.x;   // store z - x0 directly

    int4 la = *(const int4*)(gt + b * S + 4 * lane);
    int tl = gt_len[b];
    float o0 = (4 * lane + 0 < tl) ? __expf(rows[w4][la.x] - x0) : 0.f;
    float o1 = (4 * lane + 1 < tl) ? __expf(rows[w4][la.y] - x0) : 0.f;
    float o2 = (4 * lane + 2 < tl) ? __expf(rows[w4][la.z] - x0) : 0.f;
    float o3 = (4 * lane + 3 < tl) ? __expf(rows[w4][la.w] - x0) : 0.f;

    uint2 w;                                    // pack 4 bf16 (RNE)
    w.x = f32_to_bf16_rne(o0) | (f32_to_bf16_rne(o1) << 16);
    w.y = f32_to_bf16_rne(o2) | (f32_to_bf16_rne(o3) << 16);
    *(uint2*)(g16 + (size_t)wid * 512 + lane * 8) = w;
}

// Fused bidirectional scan: B blocks x 1 wave. Both half-scans interleaved
// in one instruction stream (dual-chain ILP); junction dot in-register.
__global__ __launch_bounds__(64, 1) void ctc_scan_bi(
    const char*  __restrict__ g16,
    const int*   __restrict__ pred_len,
    const int*   __restrict__ gt,
    const int*   __restrict__ gt_len,
    const float* __restrict__ z,      // pre-normalized: z_t - x0_t
    int* gdone, float* lossb,
    float* __restrict__ out,
    int T, int S, int B)
{
    const int b    = blockIdx.x;
    const int lane = threadIdx.x;
    const int len  = pred_len[b];     // host guards T>=96 -> len>=48
    const int tl   = gt_len[b];
    const int L    = 2 * tl + 1;
    const int m    = (len + 1) >> 1;  // fwd rows; nb = len-m; m in {nb,nb+1}
    const int nb   = len - m;         // >= 23 for len >= 48

    int4 la = *(const int4*)(gt + b * S + 4 * lane);
    int law_up = __shfl_up(la.w, 1, 64);     // init-time only: DS ok here
    int lax_dn = __shfl_down(la.x, 1, 64);
    const double sk0 = (lane > 0 && la.x != law_up) ? 1.0 : 0.0; // skip[8i+1]
    const double sk1 = (la.y != la.x) ? 1.0 : 0.0;               // skip[8i+3]
    const double sk2 = (la.z != la.y) ? 1.0 : 0.0;               // skip[8i+5]
    const double sk3 = (la.w != la.z) ? 1.0 : 0.0;               // skip[8i+7]
    const double sk4 = (lax_dn != la.w) ? 1.0 : 0.0;             // skip[8i+9]

    const char* gb = g16 + (size_t)b * T * 512 + lane * 8;

    uint2  rawf[16], rawb[16];        // two 16-deep bf16 rings (64 VGPR)
    double uf[9], ub[9];
    int Kf = 0, Kb = 0;

    auto RESCALE_F = [&]() {
        double mx = uf[0];
        #pragma unroll
        for (int j = 1; j < 9; ++j) mx = fmax(mx, uf[j]);
        #pragma unroll
        for (int off = 32; off >= 1; off >>= 1)
            mx = fmax(mx, __shfl_xor(mx, off, 64));
        int k = ((__double2hiint(mx) >> 20) & 0x7ff) - 1023;
        #pragma unroll
        for (int j = 0; j < 9; ++j) uf[j] = ldexp(uf[j], -k);  // exact
        Kf += k;
    };
    auto RESCALE_B = [&]() {
        double mx = ub[0];
        #pragma unroll
        for (int j = 1; j < 9; ++j) mx = fmax(mx, ub[j]);
        #pragma unroll
        for (int off = 32; off >= 1; off >>= 1)
            mx = fmax(mx, __shfl_xor(mx, off, 64));
        int k = ((__double2hiint(mx) >> 20) & 0x7ff) - 1023;
        #pragma unroll
        for (int j = 0; j < 9; ++j) ub[j] = ldexp(ub[j], -k);
        Kb += k;
    };

    // ---------------- init forward (rows 0..15 + prefetch row 16) ---------
    #pragma unroll
    for (int i = 0; i < 16; ++i)
        rawf[i] = *(const uint2*)(gb + (size_t)i * 512);
    #pragma unroll
    for (int j = 0; j < 9; ++j) uf[j] = 0.0;
    if (lane == 0) {
        uf[0] = 1.0;
        uf[1] = (double)__uint_as_float(rawf[0].x << 16);   // g(0, slot1)
    }
    rawf[0] = *(const uint2*)(gb + (size_t)16 * 512);
    const char* pff = gb + (size_t)17 * 512;

    // ---------------- init backward (rows len-1..len-16) ------------------
    #pragma unroll
    for (int i = 0; i < 16; ++i)
        rawb[i] = *(const uint2*)(gb + (size_t)(len - 1 - i) * 512);
    #pragma unroll
    for (int j = 0; j < 8; ++j) {
        int s = 8 * lane + j;
        ub[j] = (s == 2 * tl || s == 2 * tl - 1) ? 1.0 : 0.0;
    }
    ub[8] = (lane == 63 && L == 513) ? 1.0 : 0.0;   // slot 512 (lane 63)
    const char* pfb = gb + (size_t)(len - 17) * 512;

    auto FSTEP = [&](int i) {   // i MUST be compile-time constant (r5)
        uint2 q = rawf[i];
        rawf[i] = *(const uint2*)pff; pff += 512;   // prefetch row +16
        double um1 = dpp_shr1_f64(uf[7]);           // lane0 -> 0 (exact)
        double gx = (double)__uint_as_float(q.x << 16);
        double gy = (double)__uint_as_float(q.x & 0xffff0000u);
        double gz = (double)__uint_as_float(q.y << 16);
        double gw = (double)__uint_as_float(q.y & 0xffff0000u);
        uf[8] = uf[8] + uf[7];
        uf[7] = (fma(sk3, uf[5], uf[6]) + uf[7]) * gw;
        uf[6] = uf[6] + uf[5];
        uf[5] = (fma(sk2, uf[3], uf[4]) + uf[5]) * gz;
        uf[4] = uf[4] + uf[3];
        uf[3] = (fma(sk1, uf[1], uf[2]) + uf[3]) * gy;
        uf[2] = uf[2] + uf[1];
        uf[1] = (fma(sk0, um1, uf[0]) + uf[1]) * gx;
        uf[0] = uf[0] + um1;
    };

    auto BSTEP = [&](int i) {   // i MUST be compile-time constant
        uint2 q = rawb[i];
        rawb[i] = *(const uint2*)pfb; pfb -= 512;   // prefetch row -16
        double d0 = dpp_shl1_f64(ub[0]);            // slot 8i+8 (pre-step)
        if (lane == 63) d0 = ub[8];
        double gx = (double)__uint_as_float(q.x << 16);
        double gy = (double)__uint_as_float(q.x & 0xffff0000u);
        double gz = (double)__uint_as_float(q.y << 16);
        double gw = (double)__uint_as_float(q.y & 0xffff0000u);
        double p1 = gx * ub[1], p3 = gy * ub[3];
        double p5 = gz * ub[5], p7 = gw * ub[7];
        double dp = dpp_shl1_f64(p1);               // lane63 -> 0
        ub[0] = ub[0] + p1;
        ub[1] = fma(sk1, p3, ub[2]) + p1;
        ub[2] = ub[2] + p3;
        ub[3] = fma(sk2, p5, ub[4]) + p3;
        ub[4] = ub[4] + p5;
        ub[5] = fma(sk3, p7, ub[6]) + p5;
        ub[6] = ub[6] + p7;
        ub[7] = fma(sk4, dp, d0) + p7;
    };

    // phase 1: fwd steps 1..15 interleaved with bwd steps 0..15
    #pragma unroll
    for (int i = 0; i < 16; ++i) {
        if (i >= 1) FSTEP(i);
        BSTEP(i);
    }
    // steady state: dual-chain 16-row chunks; rescale every 64 steps/chain
    int tb = 16, kb = 16;
    for (; kb + 16 <= nb; tb += 16, kb += 16) {   // m >= nb => fwd fits too
        #pragma unroll
        for (int i = 0; i < 16; ++i) { FSTEP(i); BSTEP(i); }
        if (((kb + 16) & 63) == 0) { RESCALE_F(); RESCALE_B(); }
    }
    // tails: fwd remaining <= 16 (m <= nb+1), bwd remaining <= 15
    #pragma unroll
    for (int i = 0; i < 16; ++i) {
        if (tb + i < m)  FSTEP(i);
        if (kb + i < nb) BSTEP(i);
    }
    RESCALE_F(); RESCALE_B();     // normalize before junction

    // -------- junction: in-register dot (both halves in this wave) --------
    double c = 0.0;
    #pragma unroll
    for (int j = 0; j < 8; ++j) c = fma(uf[j], ub[j], c);
    if (lane == 63) c = fma(uf[8], ub[8], c);
    #pragma unroll
    for (int off = 32; off >= 1; off >>= 1) c += __shfl_xor(c, off, 64);

    // zs = sum over t<len of (z_t - x0_t); unrolled x8 for issue batching
    double zs = 0.0;
    const float* zb = z + b * T;
    int t = lane;
    for (; t + 448 < len; t += 512) {
        float a0 = zb[t],       a1 = zb[t + 64],  a2 = zb[t + 128];
        float a3 = zb[t + 192], a4 = zb[t + 256], a5 = zb[t + 320];
        float a6 = zb[t + 384], a7 = zb[t + 448];
        zs += (((double)a0 + a1) + ((double)a2 + a3))
            + (((double)a4 + a5) + ((double)a6 + a7));
    }
    for (; t < len; t += 64) zs += (double)zb[t];
    #pragma unroll
    for (int off = 32; off >= 1; off >>= 1) zs += __shfl_xor(zs, off, 64);

    if (lane == 0) {
        double logp = log(c)
                    + (double)(Kf + Kb) * 0.6931471805599453 - zs;
        double loss = -logp;
        if (!(loss < 1e10)) loss = 0.0;   // zero_infinity (+inf / NaN)
        if (loss < 0.0)     loss = 0.0;   // CTC loss >= 0: circuit breaker
        lossb[b] = (float)(loss / (double)tl);
        __threadfence();
        int pg = __hip_atomic_fetch_add(gdone, 1, __ATOMIC_ACQ_REL,
                                        __HIP_MEMORY_SCOPE_AGENT);
        if (pg == B - 1) {                // last batch: deterministic mean
            __threadfence();
            float ssum = 0.0f;
            for (int i = 0; i < B; ++i) ssum += lossb[i];
            out[0] = ssum / (float)B;
        }
    }
}

// ======================= PATH B (fallback: proven round-3) ==================
constexpr int SPL  = 9;
constexpr int RING = 32;

__global__ void ctc_reduce_kernel(const float* __restrict__ ls,
                                  float* __restrict__ out, int B)
{
    if (blockIdx.x == 0 && threadIdx.x == 0) {
        float s = 0.0f;
        for (int i = 0; i < B; ++i) s += ls[i];
        out[0] = s / (float)B;
    }
}

__global__ __launch_bounds__(256) void softmax_z_kernel(
    const float* __restrict__ pred, float* __restrict__ z, int nrows)
{
    int w    = blockIdx.x * 4 + (threadIdx.x >> 6);
    int lane = threadIdx.x & 63;
    if (w >= nrows) return;
    const float2* p = (const float2*)pred;
    float2 v = p[(size_t)w * 64 + lane];
    float s = __expf(v.x) + __expf(v.y);
    #pragma unroll
    for (int off = 32; off >= 1; off >>= 1) s += __shfl_xor(s, off, 64);
    if (lane == 0) z[w] = __logf(s);
}

__device__ __forceinline__ void ctc_step_fb(
    const float* __restrict__ rowbase, const int* __restrict__ goff,
    const double* __restrict__ skd, double (&u)[SPL], int lane)
{
    float gf[SPL];
    #pragma unroll
    for (int j = 0; j < SPL; ++j)
        gf[j] = *(const float*)((const char*)rowbase + goff[j]);
    double um1 = __shfl_up(u[8], 1, 64);
    double um2 = __shfl_up(u[7], 1, 64);
    if (lane == 0) { um1 = 0.0; um2 = 0.0; }
    #pragma unroll
    for (int jj = 0; jj < SPL; ++jj) {
        int j = SPL - 1 - jj;
        double a2 = (j >= 1) ? u[j - 1] : um1;
        double a3 = (j >= 2) ? u[j - 2] : ((j == 1) ? um1 : um2);
        double t  = fma(skd[j], a3, a2) + u[j];
        u[j] = t * (double)gf[j];
    }
}

__device__ __forceinline__ void ctc_rescale_fb(double (&u)[SPL], int& K)
{
    double m = u[0];
    #pragma unroll
    for (int j = 1; j < SPL; ++j) m = fmax(m, u[j]);
    #pragma unroll
    for (int off = 32; off >= 1; off >>= 1) m = fmax(m, __shfl_xor(m, off, 64));
    if (m > 0.0) {
        int e = (__double2hiint(m) >> 20) & 0x7ff;
        int k = e - 1023;
        #pragma unroll
        for (int j = 0; j < SPL; ++j) u[j] = ldexp(u[j], -k);
        K += k;
    }
}

__global__ __launch_bounds__(64) void ctc_scan_kernel(
    const float* __restrict__ pred, const int* __restrict__ pred_len,
    const int* __restrict__ gt, const int* __restrict__ gt_len,
    const float* __restrict__ z, float* __restrict__ loss_out, int T, int S)
{
    const int b    = blockIdx.x;
    const int lane = threadIdx.x;
    const int len  = pred_len[b];
    const int tl   = gt_len[b];
    const int L    = 2 * tl + 1;

    __shared__ float ring[RING][V];
    __shared__ int   gts[512];

    for (int i = lane; i < S; i += 64) gts[i] = gt[b * S + i];
    __syncthreads();

    int    goff[SPL];
    double skd[SPL];
    #pragma unroll
    for (int j = 0; j < SPL; ++j) {
        int s = SPL * lane + j;
        int e = 0, ep = 0;
        if (s < L && (s & 1)) e = gts[s >> 1];
        if (s >= 2 && s < L && (s & 1)) ep = gts[(s - 2) >> 1];
        goff[j] = e * 4;
        skd[j]  = (s >= 2 && s < L && e != 0 && e != ep) ? 1.0 : 0.0;
    }

    const float2* rowp = (const float2*)(pred + (size_t)b * T * V);
    float2 raw[16];

    #pragma unroll
    for (int i = 0; i < 16; ++i) raw[i] = rowp[(size_t)i * 64 + lane];
    #pragma unroll
    for (int i = 0; i < 16; ++i) {
        float2 w; w.x = __expf(raw[i].x); w.y = __expf(raw[i].y);
        *(float2*)&ring[i][2 * lane] = w;
    }
    #pragma unroll
    for (int i = 0; i < 16; ++i) raw[i] = rowp[(size_t)(16 + i) * 64 + lane];
    #pragma unroll
    for (int i = 0; i < 16; ++i) {
        float2 w; w.x = __expf(raw[i].x); w.y = __expf(raw[i].y);
        *(float2*)&ring[16 + i][2 * lane] = w;
    }
    #pragma unroll
    for (int i = 0; i < 16; ++i) {
        int r = 32 + i; if (r > T - 1) r = T - 1;
        raw[i] = rowp[(size_t)r * 64 + lane];
    }

    double u[SPL];
    #pragma unroll
    for (int j = 0; j < SPL; ++j) {
        int s = SPL * lane + j;
        float w0 = *(const float*)((const char*)&ring[0][0] + goff[j]);
        u[j] = (s < 2) ? (double)w0 : 0.0;
    }
    int K = 0;

    for (int t = 1; t < 16 && t < len; ++t)
        ctc_step_fb(&ring[t & (RING - 1)][0], goff, skd, u, lane);
    ctc_rescale_fb(u, K);

    int tb = 16;
    for (; tb + 16 <= len; tb += 16) {
        #pragma unroll
        for (int i = 0; i < 16; ++i) {
            float2 w; w.x = __expf(raw[i].x); w.y = __expf(raw[i].y);
            *(float2*)&ring[(tb + 16 + i) & (RING - 1)][2 * lane] = w;
        }
        #pragma unroll
        for (int i = 0; i < 16; ++i) {
            int r = tb + 32 + i; if (r > T - 1) r = T - 1;
            raw[i] = rowp[(size_t)r * 64 + lane];
        }
        #pragma unroll
        for (int i = 0; i < 16; ++i)
            ctc_step_fb(&ring[(tb + i) & (RING - 1)][0], goff, skd, u, lane);
        ctc_rescale_fb(u, K);
    }

    for (int t = tb; t < len; ++t)
        ctc_step_fb(&ring[t & (RING - 1)][0], goff, skd, u, lane);

    double contrib = 0.0;
    #pragma unroll
    for (int j = 0; j < SPL; ++j) {
        int s = SPL * lane + j;
        if (s == L - 1 || s == L - 2) contrib += u[j];
    }
    #pragma unroll
    for (int off = 32; off >= 1; off >>= 1)
        contrib += __shfl_xor(contrib, off, 64);

    double zsum = 0.0;
    for (int t = lane; t < len; t += 64) zsum += (double)z[b * T + t];
    #pragma unroll
    for (int off = 32; off >= 1; off >>= 1)
        zsum += __shfl_xor(zsum, off, 64);

    if (lane == 0) {
        double lg    = log(contrib);
        double alpha = lg + (double)K * 0.6931471805599453 - zsum;
        double loss  = -alpha;
        if (!(loss < 1e10)) loss = 0.0;
        loss_out[b] = (float)(loss / (double)tl);
    }
}

// ======================= host =======================
extern "C" void kernel_launch(void* const* d_in, const int* in_sizes, int n_in,
                              void* d_out, int out_size, void* d_ws, size_t ws_size,
                              hipStream_t stream) {
    const float* pred = (const float*)d_in[0];   // [B, T, V] fp32
    const int*   plen = (const int*)d_in[1];     // [B]
    const int*   gts  = (const int*)d_in[2];     // [B, S]
    const int*   glen = (const int*)d_in[3];     // [B]

    const int B = in_sizes[1];
    const int S = in_sizes[2] / B;
    const int T = in_sizes[0] / (B * V);
    const size_t BT = (size_t)B * T;

    float* out = (float*)d_out;
    char*  ws  = (char*)d_ws;

    // fast-path workspace layout
    size_t off_fl = 0;                               // flags: 1024 B
    size_t off_z  = 1024;
    size_t off_g  = (off_z + BT * 4 + 1023) & ~(size_t)1023;
    size_t need   = off_g + BT * 512;                // bf16 g: 512 B/row

    bool fast_ok = (ws_size >= need) && (S == 256) && (T % 4 == 0) &&
                   (T >= 96) && (B >= 1) && (B <= 64);

    if (fast_ok) {
        int*    flags = (int*)(ws + off_fl);
        int*    gdone = flags + 64;
        float*  lossb = (float*)(ws + off_fl + 512);  // [64]
        float*  zp    = (float*)(ws + off_z);
        char*   g16   = ws + off_g;

        ctc_prelude<<<B * T / 4, 256, 0, stream>>>(pred, gts, glen, plen,
                                                   g16, zp, flags, T, S);
        ctc_scan_bi<<<B, 64, 0, stream>>>(g16, plen, gts, glen, zp,
                                          gdone, lossb, out, T, S, B);
    } else {
        float* zbuf = (float*)ws;                 // B*T
        float* lb   = zbuf + BT;                  // B
        int nrows = B * T;
        softmax_z_kernel<<<(nrows + 3) / 4, 256, 0, stream>>>(pred, zbuf, nrows);
        ctc_scan_kernel<<<B, 64, 0, stream>>>(pred, plen, gts, glen, zbuf, lb, T, S);
        ctc_reduce_kernel<<<1, 64, 0, stream>>>(lb, out, B);
    }
}